// Round 9
// baseline (139.253 us; speedup 1.0000x reference)
//
#include <hip/hip_runtime.h>
#include <math.h>

// Problem constants (fixed by setup_inputs: B=16,T=16,H=16,W=16,DIM=256)
constexpr int Bn   = 16;
constexpr int Tn   = 16;
constexpr int Sn   = 256;   // H*W
constexpr int Cn   = 256;
constexpr int NH   = 8;     // heads
constexpr int HD   = 32;    // head dim
constexpr int NW   = 8;     // n_win
constexpr int WINW = 32;    // win
constexpr float SCALE = 0.17677669529663687f; // 32^-0.5
constexpr float CEXP  = 0.2550756272475434f;  // SCALE * log2(e)

typedef __attribute__((ext_vector_type(8))) short bf16x8;
typedef __attribute__((ext_vector_type(4))) float f32x4;

__device__ inline float bf2f(unsigned short u) {
  return __uint_as_float(((unsigned int)u) << 16);
}
__device__ inline unsigned short f2bf(float f) {  // round-to-nearest-even
  unsigned int u = __float_as_uint(f);
  u += 0x7FFFu + ((u >> 16) & 1u);
  return (unsigned short)(u >> 16);
}
__device__ inline unsigned int cvtpk_bf16(float lo, float hi) {
  unsigned int r;
  asm("v_cvt_pk_bf16_f32 %0, %1, %2" : "=v"(r) : "v"(lo), "v"(hi));
  return r;
}
__device__ inline float fast_exp2(float x) {
  float r;
  asm("v_exp_f32 %0, %1" : "=v"(r) : "v"(x));
  return r;
}
__device__ inline void gload16(const void* g, const void* l) {
  // async global->LDS, 16B per lane. LDS dest = wave-uniform base + lane*16.
  __builtin_amdgcn_global_load_lds(
      (const __attribute__((address_space(1))) void*)g,
      (__attribute__((address_space(3))) void*)l, 16, 0, 0);
}

// ---------------------------------------------------------------------------
// K0 (merged prep): blk<2048 -> window sums + x->bf16 (float4/ushort4
// vectorized, G13); 2048..2815 -> qkv weight transpose; 2816..3071 -> proj
// weight transpose. Branch is per-block uniform.
// ---------------------------------------------------------------------------
__global__ __launch_bounds__(256) void k_prep(const float* __restrict__ x,
                                              const float* __restrict__ w_qkv,
                                              const float* __restrict__ w_proj,
                                              float* __restrict__ xs,
                                              unsigned short* __restrict__ xb,
                                              unsigned short* __restrict__ wtb,
                                              float* __restrict__ wtf,
                                              unsigned short* __restrict__ wpt) {
  __shared__ __align__(16) float psum[4][256];
  const int blk = blockIdx.x;
  const int tid = threadIdx.x;
  if (blk < 2048) {
    // 32 rows x 256 cols; thread: rg=tid>>6 rows rg*8..+7, cg=tid&63 col grp
    const size_t row0 = (size_t)blk * 32;
    const int rg = tid >> 6, cg = tid & 63;
    float4 s4 = {0.f, 0.f, 0.f, 0.f};
#pragma unroll
    for (int r = 0; r < 8; ++r) {
      const size_t row = row0 + rg * 8 + r;
      const float4 v = *(const float4*)(x + row * 256 + cg * 4);
      s4.x += v.x; s4.y += v.y; s4.z += v.z; s4.w += v.w;
      ushort4 u;
      u.x = f2bf(v.x); u.y = f2bf(v.y); u.z = f2bf(v.z); u.w = f2bf(v.w);
      *(ushort4*)(xb + row * 256 + cg * 4) = u;
    }
    *(float4*)&psum[rg][cg * 4] = s4;
    __syncthreads();
    const int c = tid;
    xs[(size_t)blk * 256 + c] =
        (psum[0][c] + psum[1][c]) + (psum[2][c] + psum[3][c]);
  } else if (blk < 2816) {
    const int co = blk - 2048;     // output row = original column 0..767
    const float val = w_qkv[(size_t)tid * 768 + co];
    wtf[(size_t)co * 256 + tid] = val;
    wtb[(size_t)co * 256 + tid] = f2bf(val);
  } else {
    const int co = blk - 2816;
    wpt[(size_t)co * 256 + tid] = f2bf(w_proj[(size_t)tid * 256 + co]);
  }
}

// ---------------------------------------------------------------------------
// K1 (fused routing): block per bt (256 blocks). q_reg/k_reg for 8 windows x
// 8 heads (exact fp32 via linearity), sim per head, top-4.
// ---------------------------------------------------------------------------
__global__ __launch_bounds__(256) void k_regtopk(const float* __restrict__ xs,
                                                 const float* __restrict__ wtf,
                                                 const float* __restrict__ bias,
                                                 int* __restrict__ idxout) {
  __shared__ __align__(16) float xl[8][256];   // window sums for this bt
  __shared__ __align__(16) float ql[8][256];   // q_reg[n][c]
  __shared__ __align__(16) float kl[8][256];   // k_reg[n][c]
  __shared__ float sim[8][8][8];               // [h][n][m]
  const int bt = blockIdx.x;          // 0..255
  const int tid = threadIdx.x;
  {
    const float4* src = (const float4*)(xs + (size_t)bt * 2048);
    float4* dst = (float4*)&xl[0][0];
    dst[tid] = src[tid];
    dst[tid + 256] = src[tid + 256];
  }
  __syncthreads();
  {
    float accq[8] = {}, acck[8] = {};
    const float4* wq = (const float4*)(wtf + (size_t)tid * 256);
    const float4* wk = (const float4*)(wtf + (size_t)(256 + tid) * 256);
#pragma unroll 4
    for (int i = 0; i < 64; ++i) {
      const float4 a = wq[i];
      const float4 b = wk[i];
#pragma unroll
      for (int n = 0; n < 8; ++n) {
        const float4 xv = *(const float4*)&xl[n][i * 4];
        accq[n] = fmaf(xv.x, a.x,
                  fmaf(xv.y, a.y, fmaf(xv.z, a.z, fmaf(xv.w, a.w, accq[n]))));
        acck[n] = fmaf(xv.x, b.x,
                  fmaf(xv.y, b.y, fmaf(xv.z, b.z, fmaf(xv.w, b.w, acck[n]))));
      }
    }
    const float bq = 32.f * bias[tid];
    const float bk = 32.f * bias[256 + tid];
#pragma unroll
    for (int n = 0; n < 8; ++n) {
      ql[n][tid] = accq[n] + bq;
      kl[n][tid] = acck[n] + bk;
    }
  }
  __syncthreads();
  {
    const int h = tid >> 5, n = (tid >> 2) & 7, m0 = (tid & 3) * 2;
#pragma unroll
    for (int mm = 0; mm < 2; ++mm) {
      const int m = m0 + mm;
      float s = 0.f;
#pragma unroll
      for (int d = 0; d < 32; ++d)
        s = fmaf(ql[n][h * 32 + d], kl[m][h * 32 + d], s);
      sim[h][n][m] = s;
    }
  }
  __syncthreads();
  if (tid < 64) {
    const int h = tid >> 3, n = tid & 7;
    float vals[8];
#pragma unroll
    for (int m = 0; m < 8; ++m) vals[m] = sim[h][n][m];
#pragma unroll
    for (int j = 0; j < 4; ++j) {
      float best = -3.402823466e38f;
      int bi = 0;
#pragma unroll
      for (int m = 0; m < 8; ++m)
        if (vals[m] > best) { best = vals[m]; bi = m; }  // ties -> lowest idx
      vals[bi] = -3.402823466e38f;
      idxout[(((size_t)bt * 8 + h) * 8 + n) * 4 + j] = bi;
    }
  }
}

// ---------------------------------------------------------------------------
// K2: qkv GEMM via bf16 MFMA. XCD-bijective swizzle (3072 = 8*384).
// R9: reverted to single-buffer (R7) — R8's explicit dbuf cut occupancy
// 24->17.6% and regressed 7 µs (m99/m132 lesson re-verified).
// ---------------------------------------------------------------------------
__global__ __launch_bounds__(256) void k_qkv_mfma(
    const unsigned short* __restrict__ Xb,   // [65536][256] bf16 row-major
    const unsigned short* __restrict__ Wt,   // [768][256] bf16 (n-major)
    const float* __restrict__ bias,
    unsigned short* __restrict__ q,
    unsigned short* __restrict__ k,
    unsigned short* __restrict__ v) {
  __shared__ short As[128 * 64];   // 16 KB, [row m][k] with XOR swizzle
  __shared__ short Bs[128 * 64];   // 16 KB, [row n][k] with XOR swizzle
  const int tid = threadIdx.x;
  const int wid = tid >> 6, lane = tid & 63;
  const int p = blockIdx.x;              // physical id; XCD ~ p&7
  const int bidx = (p & 7) * 384 + (p >> 3);   // bijective (3072 = 8*384)
  const int mt = bidx / 6, nt = bidx - mt * 6;
  const int row0 = mt * 128, col0 = nt * 128;
  const int wm = (wid >> 1) * 64, wn = (wid & 1) * 64;

  f32x4 acc[4][4] = {};

  const int lr = lane >> 3, lc = lane & 7;   // staging: row-in-8, 16B group

  for (int kk0 = 0; kk0 < 256; kk0 += 64) {
#pragma unroll
    for (int j = 0; j < 4; ++j) {
      const int r = wid * 32 + j * 8 + lr;             // tile row 0..127
      const int gsw = (lc ^ (r & 7)) * 8;              // pre-swizzled k-group
      gload16(Xb + (size_t)(row0 + r) * 256 + kk0 + gsw,
              (const char*)As + (wid * 32 + j * 8) * 128);
      gload16(Wt + (size_t)(col0 + r) * 256 + kk0 + gsw,
              (const char*)Bs + (wid * 32 + j * 8) * 128);
    }
    __syncthreads();

#pragma unroll
    for (int ks = 0; ks < 2; ++ks) {
      const int g = ks * 4 + (lane >> 4);   // 16B group within 128B row
      bf16x8 af[4], bfr[4];
#pragma unroll
      for (int i = 0; i < 4; ++i) {
        const int rm = wm + i * 16 + (lane & 15);
        af[i] = *(const bf16x8*)((const char*)As + rm * 128 + 16 * (g ^ (rm & 7)));
        const int rn = wn + i * 16 + (lane & 15);
        bfr[i] = *(const bf16x8*)((const char*)Bs + rn * 128 + 16 * (g ^ (rn & 7)));
      }
#pragma unroll
      for (int i = 0; i < 4; ++i)
#pragma unroll
        for (int j = 0; j < 4; ++j)
          acc[i][j] = __builtin_amdgcn_mfma_f32_16x16x32_bf16(
              af[i], bfr[j], acc[i][j], 0, 0, 0);
    }
    __syncthreads();
  }

  const int cl = lane & 15, rg = lane >> 4;
#pragma unroll
  for (int j = 0; j < 4; ++j) {
    const int n = col0 + wn + j * 16 + cl;   // qkv column 0..767
    const float bia = bias[n];
    const int pp = n >> 8, hh = (n >> 5) & 7, dd = n & 31;
    unsigned short* dst = (pp == 0) ? q : (pp == 1) ? k : v;
#pragma unroll
    for (int i = 0; i < 4; ++i) {
      const int mbase = row0 + wm + i * 16 + rg * 4;
#pragma unroll
      for (int r = 0; r < 4; ++r) {
        const int m = mbase + r;                 // token row
        const int bt = m >> 8, s = m & 255;
        dst[((size_t)(bt * NH + hh) * Sn + s) * HD + dd] = f2bf(acc[i][j][r] + bia);
      }
    }
  }
}

// ---------------------------------------------------------------------------
// K3: gathered attention via bf16 MFMA (R7 version, unchanged).
// ---------------------------------------------------------------------------
__global__ __launch_bounds__(256) void k_attn_mfma(
    const unsigned short* __restrict__ qb,
    const unsigned short* __restrict__ kb,
    const unsigned short* __restrict__ vb,
    const int* __restrict__ idx,
    unsigned short* __restrict__ ao) {
  __shared__ __align__(16) short kx[256 * 32];        // 16 KB  (token-major, swizzled)
  __shared__ __align__(16) short vt[32 * 264];        // 16.5 KB (d-major, padded)
  __shared__ __align__(16) unsigned int pl[4][32 * 35];  // 17.5 KB (per-wave P)
  __shared__ float sbuf[4][32];                       // row sums
  const int bth = blockIdx.x;          // 0..2047
  const int bt = bth >> 3, h = bth & 7;
  const int tid = threadIdx.x;
  const int wid = tid >> 6, l = tid & 63;
  const int g = l >> 4, q15 = l & 15;
  const unsigned short* kg = kb + (size_t)bth * 8192;
  const unsigned short* vg = vb + (size_t)bth * 8192;
  const unsigned short* qg = qb + (size_t)bth * 8192;

  // ---- stage K (swizzled: LDS group cst holds global group cst^((t>>1)&3))
  {
    const int tloc = tid >> 2, cst = tid & 3;
#pragma unroll
    for (int it = 0; it < 4; ++it) {
      const int t = it * 64 + tloc;
      const int csrc = cst ^ ((t >> 1) & 3);
      gload16((const char*)kg + t * 64 + csrc * 16,
              (const char*)kx + it * 4096 + wid * 1024);
    }
  }
  // ---- stage V transposed
  {
    const int t = tid;
    unsigned short us[32];
#pragma unroll
    for (int i = 0; i < 4; ++i)
      *(int4*)(us + 8 * i) = ((const int4*)(vg + (size_t)t * 32))[i];
#pragma unroll
    for (int d = 0; d < 32; ++d) vt[d * 264 + t] = us[d];
  }
  __syncthreads();

#pragma unroll
  for (int ww = 0; ww < 2; ++ww) {
    const int wi = wid + ww * 4;                      // window 0..7
    const bf16x8 qf0 = *(const bf16x8*)(qg + (wi * 32 + q15) * 32 + g * 8);
    const bf16x8 qf1 = *(const bf16x8*)(qg + (wi * 32 + 16 + q15) * 32 + g * 8);
    const int4 s4 = *(const int4*)(idx + ((size_t)bth * 8 + wi) * 4);
    const int sel[4] = {s4.x, s4.y, s4.z, s4.w};

    // ---- QK^T (swapped): st[mt][nt], token row = 16mt+4g+r, q col = 16nt+q15
    f32x4 st[8][2] = {};
    __builtin_amdgcn_s_setprio(1);
#pragma unroll
    for (int mt = 0; mt < 8; ++mt) {
      const int t = sel[mt >> 1] * 32 + (mt & 1) * 16 + q15;
      const bf16x8 kf =
          *(const bf16x8*)((const char*)kx + t * 64 + (g ^ ((t >> 1) & 3)) * 16);
      st[mt][0] = __builtin_amdgcn_mfma_f32_16x16x32_bf16(kf, qf0, st[mt][0], 0, 0, 0);
      st[mt][1] = __builtin_amdgcn_mfma_f32_16x16x32_bf16(kf, qf1, st[mt][1], 0, 0, 0);
    }
    __builtin_amdgcn_s_setprio(0);

    // ---- exp + row sums (no max-sub; rows lane-local, reduce over g-groups)
    float sm0 = 0.f, sm1 = 0.f;
#pragma unroll
    for (int mt = 0; mt < 8; ++mt)
#pragma unroll
      for (int r = 0; r < 4; ++r) {
        const float e0 = fast_exp2(st[mt][0][r] * CEXP);
        const float e1 = fast_exp2(st[mt][1][r] * CEXP);
        st[mt][0][r] = e0; sm0 += e0;
        st[mt][1][r] = e1; sm1 += e1;
      }
    sm0 += __shfl_xor(sm0, 16); sm0 += __shfl_xor(sm0, 32);
    sm1 += __shfl_xor(sm1, 16); sm1 += __shfl_xor(sm1, 32);
    sbuf[wid][q15] = sm0;
    sbuf[wid][16 + q15] = sm1;

    // ---- PV in two 64-token chunks through per-wave P buffer
    f32x4 oa[2][2] = {};
#pragma unroll
    for (int c = 0; c < 2; ++c) {
#pragma unroll
      for (int m3 = 0; m3 < 4; ++m3) {
        const int mt = c * 4 + m3;
        const int tl2 = m3 * 8 + 2 * g;
#pragma unroll
        for (int nt = 0; nt < 2; ++nt) {
          const int row = nt * 16 + q15;
          pl[wid][row * 35 + tl2]     = cvtpk_bf16(st[mt][nt][0], st[mt][nt][1]);
          pl[wid][row * 35 + tl2 + 1] = cvtpk_bf16(st[mt][nt][2], st[mt][nt][3]);
        }
      }
      __builtin_amdgcn_s_setprio(1);
#pragma unroll
      for (int a = 0; a < 2; ++a) {
        const bf16x8 pa0 = *(const bf16x8*)((const char*)&pl[wid][0] +
                                            q15 * 140 + (a * 32 + g * 8) * 2);
        const bf16x8 pa1 = *(const bf16x8*)((const char*)&pl[wid][0] +
                                            (16 + q15) * 140 + (a * 32 + g * 8) * 2);
        const int tv = sel[c * 2 + a] * 32 + g * 8;   // gathered global token
#pragma unroll
        for (int nt = 0; nt < 2; ++nt) {
          const bf16x8 vf =
              *(const bf16x8*)((const char*)vt + (nt * 16 + q15) * 528 + tv * 2);
          oa[0][nt] = __builtin_amdgcn_mfma_f32_16x16x32_bf16(pa0, vf, oa[0][nt], 0, 0, 0);
          oa[1][nt] = __builtin_amdgcn_mfma_f32_16x16x32_bf16(pa1, vf, oa[1][nt], 0, 0, 0);
        }
      }
      __builtin_amdgcn_s_setprio(0);
    }

    // ---- normalize + store bf16 to ao[token][C]
    const size_t rowbase = (size_t)bt * 256 + wi * 32;
#pragma unroll
    for (int mtO = 0; mtO < 2; ++mtO) {
      float inv[4];
#pragma unroll
      for (int r = 0; r < 4; ++r)
        inv[r] = __builtin_amdgcn_rcpf(sbuf[wid][mtO * 16 + g * 4 + r]);
#pragma unroll
      for (int nt = 0; nt < 2; ++nt)
#pragma unroll
        for (int r = 0; r < 4; ++r) {
          const size_t tok = rowbase + mtO * 16 + g * 4 + r;
          ao[tok * 256 + h * 32 + nt * 16 + q15] = f2bf(oa[mtO][nt][r] * inv[r]);
        }
    }
  }
}

// ---------------------------------------------------------------------------
// K4: output projection via bf16 MFMA, XCD swizzle, single-buffer (R7).
// ---------------------------------------------------------------------------
__global__ __launch_bounds__(256) void k_proj_mfma(
    const unsigned short* __restrict__ AO,   // [65536][256] bf16
    const unsigned short* __restrict__ Wp,   // [256][256] bf16 (n-major)
    const float* __restrict__ bias,
    float* __restrict__ out) {
  __shared__ short As[128 * 64];
  __shared__ short Bs[128 * 64];
  const int tid = threadIdx.x;
  const int wid = tid >> 6, lane = tid & 63;
  const int p = blockIdx.x;
  const int bidx = (p & 7) * 128 + (p >> 3);   // bijective (1024 = 8*128)
  const int mt = bidx >> 1, nt = bidx & 1;
  const int row0 = mt * 128, col0 = nt * 128;
  const int wm = (wid >> 1) * 64, wn = (wid & 1) * 64;

  f32x4 acc[4][4] = {};
  const int lr = lane >> 3, lc = lane & 7;

  for (int kk0 = 0; kk0 < 256; kk0 += 64) {
#pragma unroll
    for (int j = 0; j < 4; ++j) {
      const int r = wid * 32 + j * 8 + lr;
      const int gsw = (lc ^ (r & 7)) * 8;
      gload16(AO + (size_t)(row0 + r) * 256 + kk0 + gsw,
              (const char*)As + (wid * 32 + j * 8) * 128);
      gload16(Wp + (size_t)(col0 + r) * 256 + kk0 + gsw,
              (const char*)Bs + (wid * 32 + j * 8) * 128);
    }
    __syncthreads();

#pragma unroll
    for (int ks = 0; ks < 2; ++ks) {
      const int g = ks * 4 + (lane >> 4);
      bf16x8 af[4], bfr[4];
#pragma unroll
      for (int i = 0; i < 4; ++i) {
        const int rm = wm + i * 16 + (lane & 15);
        af[i] = *(const bf16x8*)((const char*)As + rm * 128 + 16 * (g ^ (rm & 7)));
        const int rn = wn + i * 16 + (lane & 15);
        bfr[i] = *(const bf16x8*)((const char*)Bs + rn * 128 + 16 * (g ^ (rn & 7)));
      }
#pragma unroll
      for (int i = 0; i < 4; ++i)
#pragma unroll
        for (int j = 0; j < 4; ++j)
          acc[i][j] = __builtin_amdgcn_mfma_f32_16x16x32_bf16(
              af[i], bfr[j], acc[i][j], 0, 0, 0);
    }
    __syncthreads();
  }

  const int cl = lane & 15, rg = lane >> 4;
#pragma unroll
  for (int j = 0; j < 4; ++j) {
    const int n = col0 + wn + j * 16 + cl;
    const float bia = bias[n];
#pragma unroll
    for (int i = 0; i < 4; ++i) {
      const int mbase = row0 + wm + i * 16 + rg * 4;
#pragma unroll
      for (int r = 0; r < 4; ++r)
        out[(size_t)(mbase + r) * 256 + n] = acc[i][j][r] + bia;
    }
  }
}

// ---------------------------------------------------------------------------
extern "C" void kernel_launch(void* const* d_in, const int* in_sizes, int n_in,
                              void* d_out, int out_size, void* d_ws,
                              size_t ws_size, hipStream_t stream) {
  const float* x      = (const float*)d_in[0];
  const float* w_qkv  = (const float*)d_in[1];
  const float* b_qkv  = (const float*)d_in[2];
  const float* w_proj = (const float*)d_in[3];
  const float* b_proj = (const float*)d_in[4];
  float* out = (float*)d_out;

  // workspace layout (bytes) — ao reuses xb region (xb dead after k_qkv_mfma)
  char* ws = (char*)d_ws;
  unsigned short* xb  = (unsigned short*)(ws);                       // 32 MB
  unsigned short* ao  = (unsigned short*)(ws);                       // alias
  unsigned short* q   = (unsigned short*)(ws + ((size_t)32 << 20));  // 32 MB
  unsigned short* k   = (unsigned short*)(ws + ((size_t)64 << 20));  // 32 MB
  unsigned short* v   = (unsigned short*)(ws + ((size_t)96 << 20));  // 32 MB
  float*          xs  = (float*)(ws + ((size_t)128 << 20));          // 2 MB
  unsigned short* wtb = (unsigned short*)(ws + ((size_t)131 << 20)); // 384 KB
  unsigned short* wpt = (unsigned short*)(ws + ((size_t)131 << 20) + (512 << 10)); // 128 KB
  float*          wtf = (float*)(ws + ((size_t)132 << 20));          // 768 KB
  int*            idx = (int*)(ws + ((size_t)133 << 20));            // 256 KB

  k_prep<<<3072, 256, 0, stream>>>(x, w_qkv, w_proj, xs, xb, wtb, wtf, wpt);
  k_regtopk<<<256, 256, 0, stream>>>(xs, wtf, b_qkv, idx);
  k_qkv_mfma<<<3072, 256, 0, stream>>>(xb, wtb, b_qkv, q, k, v);
  k_attn_mfma<<<2048, 256, 0, stream>>>(q, k, v, idx, ao);
  k_proj_mfma<<<1024, 256, 0, stream>>>(ao, wpt, b_proj, out);
}

// Round 11
// 136.039 us; speedup vs baseline: 1.0236x; 1.0236x over previous
//
#include <hip/hip_runtime.h>
#include <math.h>

// Problem constants (fixed by setup_inputs: B=16,T=16,H=16,W=16,DIM=256)
constexpr int Bn   = 16;
constexpr int Tn   = 16;
constexpr int Sn   = 256;   // H*W
constexpr int Cn   = 256;
constexpr int NH   = 8;     // heads
constexpr int HD   = 32;    // head dim
constexpr int NW   = 8;     // n_win
constexpr int WINW = 32;    // win
constexpr float SCALE = 0.17677669529663687f; // 32^-0.5
constexpr float CEXP  = 0.2550756272475434f;  // SCALE * log2(e)

typedef __attribute__((ext_vector_type(8))) short bf16x8;
typedef __attribute__((ext_vector_type(4))) float f32x4;

__device__ inline float bf2f(unsigned short u) {
  return __uint_as_float(((unsigned int)u) << 16);
}
__device__ inline unsigned short f2bf(float f) {  // round-to-nearest-even
  unsigned int u = __float_as_uint(f);
  u += 0x7FFFu + ((u >> 16) & 1u);
  return (unsigned short)(u >> 16);
}
__device__ inline unsigned int cvtpk_bf16(float lo, float hi) {
  unsigned int r;
  asm("v_cvt_pk_bf16_f32 %0, %1, %2" : "=v"(r) : "v"(lo), "v"(hi));
  return r;
}
__device__ inline float fast_exp2(float x) {
  float r;
  asm("v_exp_f32 %0, %1" : "=v"(r) : "v"(x));
  return r;
}
__device__ inline void gload16(const void* g, const void* l) {
  // async global->LDS, 16B per lane. LDS dest = wave-uniform base + lane*16.
  __builtin_amdgcn_global_load_lds(
      (const __attribute__((address_space(1))) void*)g,
      (__attribute__((address_space(3))) void*)l, 16, 0, 0);
}

// ---------------------------------------------------------------------------
// K0 (merged prep): blk<2048 -> window sums + x->bf16; 2048..2815 -> qkv
// weight transpose (bf16+fp32); 2816..3071 -> proj weight transpose (bf16).
// ---------------------------------------------------------------------------
__global__ __launch_bounds__(256) void k_prep(const float* __restrict__ x,
                                              const float* __restrict__ w_qkv,
                                              const float* __restrict__ w_proj,
                                              float* __restrict__ xs,
                                              unsigned short* __restrict__ xb,
                                              unsigned short* __restrict__ wtb,
                                              float* __restrict__ wtf,
                                              unsigned short* __restrict__ wpt) {
  const int blk = blockIdx.x;
  const int tid = threadIdx.x;
  if (blk < 2048) {
    const size_t row0 = (size_t)blk * 32;  // global token row
    float acc = 0.f;
#pragma unroll
    for (int r = 0; r < 32; ++r) {
      const float val = x[(row0 + r) * Cn + tid];
      acc += val;
      xb[(row0 + r) * Cn + tid] = f2bf(val);
    }
    xs[(size_t)blk * Cn + tid] = acc;
  } else if (blk < 2816) {
    const int co = blk - 2048;     // output row = original column 0..767
    const float val = w_qkv[(size_t)tid * 768 + co];
    wtf[(size_t)co * 256 + tid] = val;
    wtb[(size_t)co * 256 + tid] = f2bf(val);
  } else {
    const int co = blk - 2816;
    wpt[(size_t)co * 256 + tid] = f2bf(w_proj[(size_t)tid * 256 + co]);
  }
}

// ---------------------------------------------------------------------------
// K1a: region-feature GEMM (fp32, exact routing path).
// reg[2048][512] = xs[2048][256] @ wtf[0:512]^T + 32*bias.
// ---------------------------------------------------------------------------
__global__ __launch_bounds__(256) void k_reg(const float* __restrict__ xs,
                                             const float* __restrict__ wtf,
                                             const float* __restrict__ bias,
                                             float* __restrict__ reg) {
  __shared__ __align__(16) float As[16][64];
  __shared__ __align__(16) float Bs[16][64];
  const int bx = blockIdx.x;       // 0..7   (col tile)
  const int by = blockIdx.y;       // 0..31  (row tile)
  const int tid = threadIdx.x;
  const int tx = tid & 15, ty = tid >> 4;
  const int row0 = by * 64, col0 = bx * 64;

  float acc[4][4] = {};

  for (int kk0 = 0; kk0 < 256; kk0 += 16) {
    const int m = tid >> 2, ks = (tid & 3) * 4;
    const float4 a4 = *reinterpret_cast<const float4*>(
        xs + (size_t)(row0 + m) * 256 + kk0 + ks);
    As[ks + 0][m] = a4.x; As[ks + 1][m] = a4.y;
    As[ks + 2][m] = a4.z; As[ks + 3][m] = a4.w;
    const float4 b4 = *reinterpret_cast<const float4*>(
        wtf + (size_t)(col0 + m) * 256 + kk0 + ks);   // wtf row = output col
    Bs[ks + 0][m] = b4.x; Bs[ks + 1][m] = b4.y;
    Bs[ks + 2][m] = b4.z; Bs[ks + 3][m] = b4.w;
    __syncthreads();
#pragma unroll
    for (int kk = 0; kk < 16; ++kk) {
      const float4 a = *reinterpret_cast<const float4*>(&As[kk][ty * 4]);
      const float4 b = *reinterpret_cast<const float4*>(&Bs[kk][tx * 4]);
      const float av[4] = {a.x, a.y, a.z, a.w};
      const float bv[4] = {b.x, b.y, b.z, b.w};
#pragma unroll
      for (int i = 0; i < 4; ++i)
#pragma unroll
        for (int j = 0; j < 4; ++j) acc[i][j] = fmaf(av[i], bv[j], acc[i][j]);
    }
    __syncthreads();
  }

  const int colb = col0 + tx * 4;
  const float4 bia = *reinterpret_cast<const float4*>(bias + colb);
#pragma unroll
  for (int i = 0; i < 4; ++i) {
    const int row = row0 + ty * 4 + i;
    float4 o;
    o.x = acc[i][0] + 32.f * bia.x; o.y = acc[i][1] + 32.f * bia.y;
    o.z = acc[i][2] + 32.f * bia.z; o.w = acc[i][3] + 32.f * bia.w;
    *reinterpret_cast<float4*>(reg + (size_t)row * 512 + colb) = o;
  }
}

// ---------------------------------------------------------------------------
// K1b: top-k. Block per (b,t,h), 64 threads. sim[8][8] from reg, top-4.
// ---------------------------------------------------------------------------
__global__ __launch_bounds__(64) void k_topk(const float* __restrict__ reg,
                                             int* __restrict__ idxout) {
  __shared__ float sq[8][32];
  __shared__ float sk[8][32];
  __shared__ float sim[8][8];
  const int bth = blockIdx.x;          // 0..2047
  const int bt = bth >> 3, h = bth & 7;
  const int t = threadIdx.x;
#pragma unroll
  for (int n = 0; n < 8; ++n) {
    const size_t rb = (size_t)(bt * 8 + n) * 512 + h * 32;
    if (t < 32) sq[n][t] = reg[rb + t];
    else        sk[n][t - 32] = reg[rb + 256 + (t - 32)];
  }
  __syncthreads();
  {
    const int nn = t >> 3, m = t & 7;
    float s = 0.f;
#pragma unroll
    for (int i = 0; i < HD; ++i) s += sq[nn][i] * sk[m][i];
    sim[nn][m] = s;
  }
  __syncthreads();
  if (t < 8) {
    float vals[8];
#pragma unroll
    for (int m = 0; m < 8; ++m) vals[m] = sim[t][m];
#pragma unroll
    for (int j = 0; j < 4; ++j) {
      float best = -3.402823466e38f;
      int bi = 0;
#pragma unroll
      for (int m = 0; m < 8; ++m)
        if (vals[m] > best) { best = vals[m]; bi = m; }  // ties -> lowest idx
      vals[bi] = -3.402823466e38f;
      idxout[((size_t)bth * 8 + t) * 4 + j] = bi;
    }
  }
}

// ---------------------------------------------------------------------------
// K2: qkv GEMM via bf16 MFMA. XCD-bijective swizzle (3072 = 8*384).
// Single-buffer (proven best: explicit dbuf regressed via occupancy, R8).
// ---------------------------------------------------------------------------
__global__ __launch_bounds__(256) void k_qkv_mfma(
    const unsigned short* __restrict__ Xb,   // [65536][256] bf16 row-major
    const unsigned short* __restrict__ Wt,   // [768][256] bf16 (n-major)
    const float* __restrict__ bias,
    unsigned short* __restrict__ q,
    unsigned short* __restrict__ k,
    unsigned short* __restrict__ v) {
  __shared__ short As[128 * 64];   // 16 KB, [row m][k] with XOR swizzle
  __shared__ short Bs[128 * 64];   // 16 KB, [row n][k] with XOR swizzle
  const int tid = threadIdx.x;
  const int wid = tid >> 6, lane = tid & 63;
  const int p = blockIdx.x;              // physical id; XCD ~ p&7
  const int bidx = (p & 7) * 384 + (p >> 3);   // bijective (3072 = 8*384)
  const int mt = bidx / 6, nt = bidx - mt * 6;
  const int row0 = mt * 128, col0 = nt * 128;
  const int wm = (wid >> 1) * 64, wn = (wid & 1) * 64;

  f32x4 acc[4][4] = {};

  const int lr = lane >> 3, lc = lane & 7;   // staging: row-in-8, 16B group

  for (int kk0 = 0; kk0 < 256; kk0 += 64) {
#pragma unroll
    for (int j = 0; j < 4; ++j) {
      const int r = wid * 32 + j * 8 + lr;             // tile row 0..127
      const int gsw = (lc ^ (r & 7)) * 8;              // pre-swizzled k-group
      gload16(Xb + (size_t)(row0 + r) * 256 + kk0 + gsw,
              (const char*)As + (wid * 32 + j * 8) * 128);
      gload16(Wt + (size_t)(col0 + r) * 256 + kk0 + gsw,
              (const char*)Bs + (wid * 32 + j * 8) * 128);
    }
    __syncthreads();

#pragma unroll
    for (int ks = 0; ks < 2; ++ks) {
      const int g = ks * 4 + (lane >> 4);   // 16B group within 128B row
      bf16x8 af[4], bfr[4];
#pragma unroll
      for (int i = 0; i < 4; ++i) {
        const int rm = wm + i * 16 + (lane & 15);
        af[i] = *(const bf16x8*)((const char*)As + rm * 128 + 16 * (g ^ (rm & 7)));
        const int rn = wn + i * 16 + (lane & 15);
        bfr[i] = *(const bf16x8*)((const char*)Bs + rn * 128 + 16 * (g ^ (rn & 7)));
      }
#pragma unroll
      for (int i = 0; i < 4; ++i)
#pragma unroll
        for (int j = 0; j < 4; ++j)
          acc[i][j] = __builtin_amdgcn_mfma_f32_16x16x32_bf16(
              af[i], bfr[j], acc[i][j], 0, 0, 0);
    }
    __syncthreads();
  }

  const int cl = lane & 15, rg = lane >> 4;
#pragma unroll
  for (int j = 0; j < 4; ++j) {
    const int n = col0 + wn + j * 16 + cl;   // qkv column 0..767
    const float bia = bias[n];
    const int pp = n >> 8, hh = (n >> 5) & 7, dd = n & 31;
    unsigned short* dst = (pp == 0) ? q : (pp == 1) ? k : v;
#pragma unroll
    for (int i = 0; i < 4; ++i) {
      const int mbase = row0 + wm + i * 16 + rg * 4;
#pragma unroll
      for (int r = 0; r < 4; ++r) {
        const int m = mbase + r;                 // token row
        const int bt = m >> 8, s = m & 255;
        dst[((size_t)(bt * NH + hh) * Sn + s) * HD + dd] = f2bf(acc[i][j][r] + bia);
      }
    }
  }
}

// ---------------------------------------------------------------------------
// K3: gathered attention via bf16 MFMA (diet softmax: no max-sub, raw
// v_exp_f32, cvt_pk bf16 packing, rcp normalize, setprio around MFMA).
// ---------------------------------------------------------------------------
__global__ __launch_bounds__(256) void k_attn_mfma(
    const unsigned short* __restrict__ qb,
    const unsigned short* __restrict__ kb,
    const unsigned short* __restrict__ vb,
    const int* __restrict__ idx,
    unsigned short* __restrict__ ao) {
  __shared__ __align__(16) short kx[256 * 32];        // 16 KB  (token-major, swizzled)
  __shared__ __align__(16) short vt[32 * 264];        // 16.5 KB (d-major, padded)
  __shared__ __align__(16) unsigned int pl[4][32 * 35];  // 17.5 KB (per-wave P)
  __shared__ float sbuf[4][32];                       // row sums
  const int bth = blockIdx.x;          // 0..2047
  const int bt = bth >> 3, h = bth & 7;
  const int tid = threadIdx.x;
  const int wid = tid >> 6, l = tid & 63;
  const int g = l >> 4, q15 = l & 15;
  const unsigned short* kg = kb + (size_t)bth * 8192;
  const unsigned short* vg = vb + (size_t)bth * 8192;
  const unsigned short* qg = qb + (size_t)bth * 8192;

  // ---- stage K (swizzled: LDS group cst holds global group cst^((t>>1)&3))
  {
    const int tloc = tid >> 2, cst = tid & 3;
#pragma unroll
    for (int it = 0; it < 4; ++it) {
      const int t = it * 64 + tloc;
      const int csrc = cst ^ ((t >> 1) & 3);
      gload16((const char*)kg + t * 64 + csrc * 16,
              (const char*)kx + it * 4096 + wid * 1024);
    }
  }
  // ---- stage V transposed
  {
    const int t = tid;
    unsigned short us[32];
#pragma unroll
    for (int i = 0; i < 4; ++i)
      *(int4*)(us + 8 * i) = ((const int4*)(vg + (size_t)t * 32))[i];
#pragma unroll
    for (int d = 0; d < 32; ++d) vt[d * 264 + t] = us[d];
  }
  __syncthreads();

#pragma unroll
  for (int ww = 0; ww < 2; ++ww) {
    const int wi = wid + ww * 4;                      // window 0..7
    const bf16x8 qf0 = *(const bf16x8*)(qg + (wi * 32 + q15) * 32 + g * 8);
    const bf16x8 qf1 = *(const bf16x8*)(qg + (wi * 32 + 16 + q15) * 32 + g * 8);
    const int4 s4 = *(const int4*)(idx + ((size_t)bth * 8 + wi) * 4);
    const int sel[4] = {s4.x, s4.y, s4.z, s4.w};

    // ---- QK^T (swapped): st[mt][nt], token row = 16mt+4g+r, q col = 16nt+q15
    f32x4 st[8][2] = {};
    __builtin_amdgcn_s_setprio(1);
#pragma unroll
    for (int mt = 0; mt < 8; ++mt) {
      const int t = sel[mt >> 1] * 32 + (mt & 1) * 16 + q15;
      const bf16x8 kf =
          *(const bf16x8*)((const char*)kx + t * 64 + (g ^ ((t >> 1) & 3)) * 16);
      st[mt][0] = __builtin_amdgcn_mfma_f32_16x16x32_bf16(kf, qf0, st[mt][0], 0, 0, 0);
      st[mt][1] = __builtin_amdgcn_mfma_f32_16x16x32_bf16(kf, qf1, st[mt][1], 0, 0, 0);
    }
    __builtin_amdgcn_s_setprio(0);

    // ---- exp + row sums (no max-sub; rows lane-local, reduce over g-groups)
    float sm0 = 0.f, sm1 = 0.f;
#pragma unroll
    for (int mt = 0; mt < 8; ++mt)
#pragma unroll
      for (int r = 0; r < 4; ++r) {
        const float e0 = fast_exp2(st[mt][0][r] * CEXP);
        const float e1 = fast_exp2(st[mt][1][r] * CEXP);
        st[mt][0][r] = e0; sm0 += e0;
        st[mt][1][r] = e1; sm1 += e1;
      }
    sm0 += __shfl_xor(sm0, 16); sm0 += __shfl_xor(sm0, 32);
    sm1 += __shfl_xor(sm1, 16); sm1 += __shfl_xor(sm1, 32);
    sbuf[wid][q15] = sm0;
    sbuf[wid][16 + q15] = sm1;

    // ---- PV in two 64-token chunks through per-wave P buffer
    f32x4 oa[2][2] = {};
#pragma unroll
    for (int c = 0; c < 2; ++c) {
#pragma unroll
      for (int m3 = 0; m3 < 4; ++m3) {
        const int mt = c * 4 + m3;
        const int tl2 = m3 * 8 + 2 * g;
#pragma unroll
        for (int nt = 0; nt < 2; ++nt) {
          const int row = nt * 16 + q15;
          pl[wid][row * 35 + tl2]     = cvtpk_bf16(st[mt][nt][0], st[mt][nt][1]);
          pl[wid][row * 35 + tl2 + 1] = cvtpk_bf16(st[mt][nt][2], st[mt][nt][3]);
        }
      }
      __builtin_amdgcn_s_setprio(1);
#pragma unroll
      for (int a = 0; a < 2; ++a) {
        const bf16x8 pa0 = *(const bf16x8*)((const char*)&pl[wid][0] +
                                            q15 * 140 + (a * 32 + g * 8) * 2);
        const bf16x8 pa1 = *(const bf16x8*)((const char*)&pl[wid][0] +
                                            (16 + q15) * 140 + (a * 32 + g * 8) * 2);
        const int tv = sel[c * 2 + a] * 32 + g * 8;   // gathered global token
#pragma unroll
        for (int nt = 0; nt < 2; ++nt) {
          const bf16x8 vf =
              *(const bf16x8*)((const char*)vt + (nt * 16 + q15) * 528 + tv * 2);
          oa[0][nt] = __builtin_amdgcn_mfma_f32_16x16x32_bf16(pa0, vf, oa[0][nt], 0, 0, 0);
          oa[1][nt] = __builtin_amdgcn_mfma_f32_16x16x32_bf16(pa1, vf, oa[1][nt], 0, 0, 0);
        }
      }
      __builtin_amdgcn_s_setprio(0);
    }

    // ---- normalize + store bf16 to ao[token][C]
    const size_t rowbase = (size_t)bt * 256 + wi * 32;
#pragma unroll
    for (int mtO = 0; mtO < 2; ++mtO) {
      float inv[4];
#pragma unroll
      for (int r = 0; r < 4; ++r)
        inv[r] = __builtin_amdgcn_rcpf(sbuf[wid][mtO * 16 + g * 4 + r]);
#pragma unroll
      for (int nt = 0; nt < 2; ++nt)
#pragma unroll
        for (int r = 0; r < 4; ++r) {
          const size_t tok = rowbase + mtO * 16 + g * 4 + r;
          ao[tok * 256 + h * 32 + nt * 16 + q15] = f2bf(oa[mtO][nt][r] * inv[r]);
        }
    }
  }
}

// ---------------------------------------------------------------------------
// K4: output projection via bf16 MFMA, XCD-bijective swizzle (nwg=1024).
// ---------------------------------------------------------------------------
__global__ __launch_bounds__(256) void k_proj_mfma(
    const unsigned short* __restrict__ AO,   // [65536][256] bf16
    const unsigned short* __restrict__ Wp,   // [256][256] bf16 (n-major)
    const float* __restrict__ bias,
    float* __restrict__ out) {
  __shared__ short As[128 * 64];
  __shared__ short Bs[128 * 64];
  const int tid = threadIdx.x;
  const int wid = tid >> 6, lane = tid & 63;
  const int p = blockIdx.x;
  const int bidx = (p & 7) * 128 + (p >> 3);   // bijective (1024 = 8*128)
  const int mt = bidx >> 1, nt = bidx & 1;
  const int row0 = mt * 128, col0 = nt * 128;
  const int wm = (wid >> 1) * 64, wn = (wid & 1) * 64;

  f32x4 acc[4][4] = {};
  const int lr = lane >> 3, lc = lane & 7;

  for (int kk0 = 0; kk0 < 256; kk0 += 64) {
#pragma unroll
    for (int j = 0; j < 4; ++j) {
      const int r = wid * 32 + j * 8 + lr;
      const int gsw = (lc ^ (r & 7)) * 8;
      gload16(AO + (size_t)(row0 + r) * 256 + kk0 + gsw,
              (const char*)As + (wid * 32 + j * 8) * 128);
      gload16(Wp + (size_t)(col0 + r) * 256 + kk0 + gsw,
              (const char*)Bs + (wid * 32 + j * 8) * 128);
    }
    __syncthreads();

#pragma unroll
    for (int ks = 0; ks < 2; ++ks) {
      const int g = ks * 4 + (lane >> 4);
      bf16x8 af[4], bfr[4];
#pragma unroll
      for (int i = 0; i < 4; ++i) {
        const int rm = wm + i * 16 + (lane & 15);
        af[i] = *(const bf16x8*)((const char*)As + rm * 128 + 16 * (g ^ (rm & 7)));
        const int rn = wn + i * 16 + (lane & 15);
        bfr[i] = *(const bf16x8*)((const char*)Bs + rn * 128 + 16 * (g ^ (rn & 7)));
      }
#pragma unroll
      for (int i = 0; i < 4; ++i)
#pragma unroll
        for (int j = 0; j < 4; ++j)
          acc[i][j] = __builtin_amdgcn_mfma_f32_16x16x32_bf16(
              af[i], bfr[j], acc[i][j], 0, 0, 0);
    }
    __syncthreads();
  }

  const int cl = lane & 15, rg = lane >> 4;
#pragma unroll
  for (int j = 0; j < 4; ++j) {
    const int n = col0 + wn + j * 16 + cl;
    const float bia = bias[n];
#pragma unroll
    for (int i = 0; i < 4; ++i) {
      const int mbase = row0 + wm + i * 16 + rg * 4;
#pragma unroll
      for (int r = 0; r < 4; ++r)
        out[(size_t)(mbase + r) * 256 + n] = acc[i][j][r] + bia;
    }
  }
}

// ---------------------------------------------------------------------------
extern "C" void kernel_launch(void* const* d_in, const int* in_sizes, int n_in,
                              void* d_out, int out_size, void* d_ws,
                              size_t ws_size, hipStream_t stream) {
  const float* x      = (const float*)d_in[0];
  const float* w_qkv  = (const float*)d_in[1];
  const float* b_qkv  = (const float*)d_in[2];
  const float* w_proj = (const float*)d_in[3];
  const float* b_proj = (const float*)d_in[4];
  float* out = (float*)d_out;

  // workspace layout (bytes) — ao reuses xb region (xb dead after k_qkv_mfma)
  char* ws = (char*)d_ws;
  unsigned short* xb  = (unsigned short*)(ws);                       // 32 MB
  unsigned short* ao  = (unsigned short*)(ws);                       // alias
  unsigned short* q   = (unsigned short*)(ws + ((size_t)32 << 20));  // 32 MB
  unsigned short* k   = (unsigned short*)(ws + ((size_t)64 << 20));  // 32 MB
  unsigned short* v   = (unsigned short*)(ws + ((size_t)96 << 20));  // 32 MB
  float*          xs  = (float*)(ws + ((size_t)128 << 20));          // 2 MB
  unsigned short* wtb = (unsigned short*)(ws + ((size_t)131 << 20)); // 384 KB
  unsigned short* wpt = (unsigned short*)(ws + ((size_t)131 << 20) + (512 << 10)); // 128 KB
  float*          wtf = (float*)(ws + ((size_t)132 << 20));          // 768 KB
  int*            idx = (int*)(ws + ((size_t)133 << 20));            // 256 KB
  float*          regf= (float*)(ws + ((size_t)136 << 20));          // 4 MB

  k_prep<<<3072, 256, 0, stream>>>(x, w_qkv, w_proj, xs, xb, wtb, wtf, wpt);
  k_reg<<<dim3(8, 32), 256, 0, stream>>>(xs, wtf, b_qkv, regf);
  k_topk<<<2048, 64, 0, stream>>>(regf, idx);
  k_qkv_mfma<<<3072, 256, 0, stream>>>(xb, wtb, b_qkv, q, k, v);
  k_attn_mfma<<<2048, 256, 0, stream>>>(q, k, v, idx, ao);
  k_proj_mfma<<<1024, 256, 0, stream>>>(ao, wpt, b_proj, out);
}